// Round 20
// baseline (111.084 us; speedup 1.0000x reference)
//
#include <hip/hip_runtime.h>
#include <stdint.h>

// Problem constants (fixed by the reference's config)
#define HH 480
#define WW 640
#define NN (HH * WW)
#define BB 8
#define PP 4
#define EPS 1e-9f

// Output-tile geometry: block owns a TW x TH OUTPUT tile. 640/64=10, 480/32=15.
#define TW 64
#define TH 32
#define HALO 12
#define RGW (TW + 2 * HALO)   // 88
#define RGH (TH + 2 * HALO)   // 56
#define RGN (RGW * RGH)       // 4928
#define NBX (WW / TW)         // 10
#define NBY (HH / TH)         // 15
#define NBLOCKS (NBX * NBY * BB)  // 1200
#define NT 512                // threads/block (8 waves; R19's 384-thr co-residency
                              // experiment REGRESSED 45->52us, occupancy 48->37%)

// Binning: sources bucketed by floor cell.
#define BINSX (TW + 1)        // 65
#define BINSY (TH + 1)        // 33
#define NBINS (BINSX * BINSY) // 2145
#define CAP 4                 // slots/bin; P(>4)~0.4% -> list path

// guaranteed-in-image source id (rel HALO,HALO) for dead predicated loads
#define SAFE_ID ((HALO << 7) | HALO)

// per-block far/overflow segment (pow2 for & mask); actual usage ~25 entries/block
#define SEGCAP 1024

__device__ __forceinline__ void gatomic(float* p, float v) {
    unsafeAtomicAdd(p, v);    // native global_atomic_add_f32, rare path only
}

// ---------------- pre-pass: interleave the i-th flow plane ----------------
__global__ __launch_bounds__(256)
void interleave_flow(const float* __restrict__ fx_all,
                     const float* __restrict__ fy_all,
                     const int* __restrict__ i_ptr,
                     float2* __restrict__ fxy2) {
    int t = blockIdx.x * blockDim.x + threadIdx.x;   // one thread per 4 pixels
    const int Q = NN / 4;
    if (t >= BB * Q) return;
    int b = t / Q, q = t - b * Q;
    int i = *i_ptr;
    const float4* fyp = (const float4*)(fy_all + (size_t)(b * PP + i) * NN);
    const float4* fxp = (const float4*)(fx_all + (size_t)(b * PP + i) * NN);
    float4 y4 = fyp[q], x4 = fxp[q];
    float4* o4 = (float4*)(fxy2 + (size_t)b * NN + (size_t)q * 4);
    o4[0] = make_float4(y4.x, x4.x, y4.y, x4.y);
    o4[1] = make_float4(y4.z, x4.z, y4.w, x4.w);
}

// Phase A: scan halo region, bin sources by floor cell (1 LDS rtn-atomic per
// source); far/overflow appended to this block's list segment (conservative
// |warp-src|>11 pre-guard). Phase B: 4-row column strip per thread,
// register-cached bin rows (named float4 ping-pong). launch_bounds (512,4):
// 128-VGPR budget -- R17/18's (512,8) forced VGPR=32, which killed the
// register row-cache and load pipelining while buying no measured residency
// (occupancy ~48% ~= 2 blocks/CU either way).
__global__ __launch_bounds__(NT, 4)
void bin_gather_splat(const float2* __restrict__ fxy2,
                      const int* __restrict__ i_ptr,
                      const int* __restrict__ tref_ptr,
                      float* __restrict__ Sw, float* __restrict__ Swy, float* __restrict__ Swx,
                      unsigned* __restrict__ segcnt, int4* __restrict__ llist,
                      float* __restrict__ out) {
    __shared__ unsigned cnt[NBINS];   // 8580 B
    __shared__ ushort4  ids4[NBINS];  // 17160 B
    __shared__ unsigned lseg;
    const int tid = threadIdx.x;
    for (int e = tid; e < NBINS; e += NT) cnt[e] = 0;
    if (tid == 0) lseg = 0;
    __syncthreads();

    const int bx = blockIdx.x, by = blockIdx.y, b = blockIdx.z;
    const int bid = (b * NBY + by) * NBX + bx;
    int4* __restrict__ lseg_base = llist + (size_t)bid * SEGCAP;
    const int tx0 = bx * TW, ty0 = by * TH;
    const float dt = (float)(*tref_ptr - *i_ptr);
    const float2* __restrict__ fp2 = fxy2 + (size_t)b * NN;
    const size_t BN = (size_t)BB * NN;

    // ---------------- phase A ----------------
    for (int sp = tid; sp < RGN; sp += NT) {
        int sy = sp / RGW, sx = sp - sy * RGW;
        int gy = ty0 - HALO + sy, gx = tx0 - HALO + sx;
        if ((unsigned)gy >= (unsigned)HH || (unsigned)gx >= (unsigned)WW) continue;
        int p = gy * WW + gx;
        float2 f2 = fp2[p];
        float fy = f2.x, fx = f2.y;
        float wyf = (float)gy + dt * fy;
        float wxf = (float)gx + dt * fx;
        // purge_unfeasible
        if (!(wyf >= 0.0f && wyf <= (float)(HH - 1) &&
              wxf >= 0.0f && wxf <= (float)(WW - 1))) continue;
        float tyf = floorf(wyf), lxf = floorf(wxf);
        int iy0 = (int)tyf, ix0 = (int)lxf;   // >= 0 (inside test)
        int br = iy0 - ty0, bc = ix0 - tx0;

        bool overflow = false;
        if (br >= -1 && br < TH && bc >= -1 && bc < TW) {
            int bin = (br + 1) * BINSX + (bc + 1);
            unsigned slot = atomicAdd(&cnt[bin], 1u);   // native ds_add_rtn_u32
            if (slot < CAP)
                ((unsigned short*)&ids4[bin])[slot] = (unsigned short)((sy << 7) | sx);
            else overflow = true;
        }
        bool interior = ((unsigned)(gx - tx0) < (unsigned)TW) &&
                        ((unsigned)(gy - ty0) < (unsigned)TH);
        // conservative far pre-guard: any far (s,N) pair has |warp-s|inf >= 12
        bool maybe_far = (fabsf(wyf - (float)gy) > 11.0f) ||
                         (fabsf(wxf - (float)gx) > 11.0f);
        if (overflow || (interior && maybe_far)) {
            float fry = wyf - tyf, frx = wxf - lxf;
            float wts[4] = {(1.0f - fry) * (1.0f - frx),
                            (1.0f - fry) * frx,
                            fry * (1.0f - frx),
                            fry * frx};
#pragma unroll
            for (int k = 0; k < 4; ++k) {
                int iy = iy0 + (k >> 1), ix = ix0 + (k & 1);
                if ((unsigned)iy >= (unsigned)HH || (unsigned)ix >= (unsigned)WW) continue;
                bool inT = ((unsigned)(iy - ty0) < (unsigned)TH) &&
                           ((unsigned)(ix - tx0) < (unsigned)TW);
                // far: s's owner must emit (tile(N) never scans s)
                int tnx = (ix >> 6) << 6;   // tile(N) origin, TW=64
                int tny = (iy >> 5) << 5;   // TH=32
                int ddx = gx < tnx ? tnx - gx : (gx > tnx + (TW - 1) ? gx - tnx - (TW - 1) : 0);
                int ddy = gy < tny ? tny - gy : (gy > tny + (TH - 1) ? gy - tny - (TH - 1) : 0);
                bool far = (ddx > HALO) || (ddy > HALO);
                if ((interior && far) || (overflow && inT)) {
                    int fi = b * NN + iy * WW + ix;
                    float w = wts[k];
                    unsigned slot = atomicAdd(&lseg, 1u);   // LDS rtn-atomic
                    if (slot < SEGCAP)
                        lseg_base[slot] = make_int4(fi, __float_as_int(w),
                                                    __float_as_int(w * fy),
                                                    __float_as_int(w * fx));
                }
            }
        }
    }
    __syncthreads();
    if (tid == 0) segcnt[bid] = lseg > SEGCAP ? SEGCAP : lseg;

    // ---------------- phase B: 4-row strip, register-cached gather ----------------
    {
        const int c  = tid & 63;          // column within tile (wave-coalesced)
        const int r0 = (tid >> 6) * 4;    // tid>>6 in 0..7 -> 4-row strips cover 32
        const float cxf = (float)(tx0 + c);

#define LOAD_SLOT(dst, idraw, nn, T) {                                        \
        bool valid = (unsigned)(T) < (nn);                                    \
        int sid = valid ? (int)(idraw) : SAFE_ID;                             \
        int sy_ = sid >> 7, sx_ = sid & 127;                                  \
        int gy_ = ty0 - HALO + sy_, gx_ = tx0 - HALO + sx_;                   \
        float2 f2_ = fp2[gy_ * WW + gx_];                                     \
        float wyf_ = (float)gy_ + dt * f2_.x;                                 \
        float wxf_ = (float)gx_ + dt * f2_.y;                                 \
        dst.x = valid ? wyf_ : -1.0e6f;  /* ay=0 -> w=0 */                    \
        dst.y = wxf_;                                                         \
        dst.z = f2_.x; dst.w = f2_.y; }

#define LOAD_ROW(d0,d1,d2,d3,d4,d5,d6,d7, brow) {                             \
        int bin0_ = (brow) * BINSX + c;                                       \
        unsigned na_ = cnt[bin0_];     ushort4 sa_ = ids4[bin0_];             \
        unsigned nb_ = cnt[bin0_ + 1]; ushort4 sb_ = ids4[bin0_ + 1];         \
        LOAD_SLOT(d0, sa_.x, na_, 0); LOAD_SLOT(d1, sa_.y, na_, 1);           \
        LOAD_SLOT(d2, sa_.z, na_, 2); LOAD_SLOT(d3, sa_.w, na_, 3);           \
        LOAD_SLOT(d4, sb_.x, nb_, 0); LOAD_SLOT(d5, sb_.y, nb_, 1);           \
        LOAD_SLOT(d6, sb_.z, nb_, 2); LOAD_SLOT(d7, sb_.w, nb_, 3); }

// indirection wrappers: register lists literal in replacement text
// (macro arg counting precedes expansion -- R15 lesson)
#define LOAD_ROW_A(brow) LOAD_ROW(a0,a1,a2,a3,a4,a5,a6,a7, brow)
#define LOAD_ROW_B(brow) LOAD_ROW(b0,b1,b2,b3,b4,b5,b6,b7, brow)

#define EVAL_SLOT(S) {                                                        \
        float ay_ = fmaxf(1.0f - fabsf(S.x - cyf), 0.0f);                     \
        float ax_ = fmaxf(1.0f - fabsf(S.y - cxf), 0.0f);                     \
        float w_ = ay_ * ax_;                                                 \
        ws += w_; wys += w_ * S.z; wxs += w_ * S.w; }

        // X set = bin row r, Y set = bin row r+1
#define EVAL_CELL(X0,X1,X2,X3,X4,X5,X6,X7, Y0,Y1,Y2,Y3,Y4,Y5,Y6,Y7, rowr) {   \
        float cyf = (float)(ty0 + (rowr));                                    \
        float ws = 0.f, wys = 0.f, wxs = 0.f;                                 \
        EVAL_SLOT(X0); EVAL_SLOT(X1); EVAL_SLOT(X2); EVAL_SLOT(X3);           \
        EVAL_SLOT(X4); EVAL_SLOT(X5); EVAL_SLOT(X6); EVAL_SLOT(X7);           \
        EVAL_SLOT(Y0); EVAL_SLOT(Y1); EVAL_SLOT(Y2); EVAL_SLOT(Y3);           \
        EVAL_SLOT(Y4); EVAL_SLOT(Y5); EVAL_SLOT(Y6); EVAL_SLOT(Y7);           \
        size_t o = (size_t)b * NN + (size_t)(ty0 + (rowr)) * WW + (tx0 + c);  \
        Sw[o] = ws; Swy[o] = wys; Swx[o] = wxs;                               \
        float d = ws + EPS;                                                   \
        out[o]      = wxs / d;                                                \
        out[BN + o] = wys / d; }

#define EVAL_CELL_AB(rowr) EVAL_CELL(a0,a1,a2,a3,a4,a5,a6,a7, \
                                     b0,b1,b2,b3,b4,b5,b6,b7, rowr)
#define EVAL_CELL_BA(rowr) EVAL_CELL(b0,b1,b2,b3,b4,b5,b6,b7, \
                                     a0,a1,a2,a3,a4,a5,a6,a7, rowr)

        float4 a0,a1,a2,a3,a4,a5,a6,a7;
        float4 b0,b1,b2,b3,b4,b5,b6,b7;
        LOAD_ROW_A(r0);
        LOAD_ROW_B(r0 + 1);
        EVAL_CELL_AB(r0 + 0);  LOAD_ROW_A(r0 + 2);
        EVAL_CELL_BA(r0 + 1);  LOAD_ROW_B(r0 + 3);
        EVAL_CELL_AB(r0 + 2);  LOAD_ROW_A(r0 + 4);
        EVAL_CELL_BA(r0 + 3);
#undef LOAD_SLOT
#undef LOAD_ROW
#undef LOAD_ROW_A
#undef LOAD_ROW_B
#undef EVAL_SLOT
#undef EVAL_CELL
#undef EVAL_CELL_AB
#undef EVAL_CELL_BA
    }
}

// ---------------- fixups for list-touched pixels (grid-stride, small grid) ----------------
__global__ __launch_bounds__(256)
void fix_add(const unsigned* __restrict__ segcnt, const int4* __restrict__ llist,
             float* __restrict__ Sw, float* __restrict__ Swy, float* __restrict__ Swx) {
    const unsigned total = NBLOCKS * SEGCAP;
    const unsigned stride = gridDim.x * blockDim.x;
    for (unsigned e = blockIdx.x * blockDim.x + threadIdx.x; e < total; e += stride) {
        unsigned seg = e / SEGCAP, idx = e & (SEGCAP - 1);
        if (idx >= segcnt[seg]) continue;
        int4 v = llist[e];
        gatomic(&Sw[v.x],  __int_as_float(v.y));
        gatomic(&Swy[v.x], __int_as_float(v.z));
        gatomic(&Swx[v.x], __int_as_float(v.w));
    }
}

__global__ __launch_bounds__(256)
void fix_write(const unsigned* __restrict__ segcnt, const int4* __restrict__ llist,
               const float* __restrict__ Sw, const float* __restrict__ Swy,
               const float* __restrict__ Swx, float* __restrict__ out) {
    const unsigned total = NBLOCKS * SEGCAP;
    const unsigned stride = gridDim.x * blockDim.x;
    for (unsigned e = blockIdx.x * blockDim.x + threadIdx.x; e < total; e += stride) {
        unsigned seg = e / SEGCAP, idx = e & (SEGCAP - 1);
        if (idx >= segcnt[seg]) continue;
        int fi = llist[e].x;                  // duplicates benign (idempotent)
        float d = Sw[fi] + EPS;
        out[fi] = Swx[fi] / d;
        out[(size_t)BB * NN + fi] = Swy[fi] / d;
    }
}

// ---------------- fallback path (R1, needs only 29.5 MB ws) ----------------

__global__ void splat_kernel(const float* __restrict__ fx_all,
                             const float* __restrict__ fy_all,
                             const int* __restrict__ i_ptr,
                             const int* __restrict__ tref_ptr,
                             float* __restrict__ sum_w,
                             float* __restrict__ sum_wy,
                             float* __restrict__ sum_wx) {
    int t = blockIdx.x * blockDim.x + threadIdx.x;
    if (t >= BB * NN) return;
    int b = t / NN;
    int p = t - b * NN;
    int i = *i_ptr;
    float dt = (float)(*tref_ptr - i);
    const float fx = fx_all[(size_t)(b * PP + i) * NN + p];
    const float fy = fy_all[(size_t)(b * PP + i) * NN + p];
    float gy = (float)(p / WW);
    float gx = (float)(p - (p / WW) * WW);
    float wy = gy + dt * fy;
    float wx = gx + dt * fx;
    bool inside = (wy >= 0.0f) && (wy <= (float)(HH - 1)) &&
                  (wx >= 0.0f) && (wx <= (float)(WW - 1));
    if (!inside) return;
    float ty = floorf(wy);
    float lx = floorf(wx);
    int base = b * NN;
#pragma unroll
    for (int k = 0; k < 4; ++k) {
        float ny = ty + (float)(k >> 1);
        float nx = lx + (float)(k & 1);
        int iy = (int)ny;
        int ix = (int)nx;
        if (iy < 0 || iy >= HH || ix < 0 || ix >= WW) continue;
        float wgt_y = fminf(fmaxf(1.0f - fabsf(wy - ny), 0.0f), 1.0f);
        float wgt_x = fminf(fmaxf(1.0f - fabsf(wx - nx), 0.0f), 1.0f);
        float w = wgt_y * wgt_x;
        int fi = base + iy * WW + ix;
        gatomic(&sum_w[fi],  w);
        gatomic(&sum_wy[fi], w * fy);
        gatomic(&sum_wx[fi], w * fx);
    }
}

__global__ void finalize_kernel(const float* __restrict__ sum_w,
                                const float* __restrict__ sum_wy,
                                const float* __restrict__ sum_wx,
                                float* __restrict__ out) {
    int t = blockIdx.x * blockDim.x + threadIdx.x;
    if (t >= BB * NN) return;
    float denom = sum_w[t] + EPS;
    out[t]                   = sum_wx[t] / denom;
    out[(size_t)BB * NN + t] = sum_wy[t] / denom;
}

// ---------------- launch ----------------

extern "C" void kernel_launch(void* const* d_in, const int* in_sizes, int n_in,
                              void* d_out, int out_size, void* d_ws, size_t ws_size,
                              hipStream_t stream) {
    const float* fx_all = (const float*)d_in[0];
    const float* fy_all = (const float*)d_in[1];
    const int* i_ptr    = (const int*)d_in[2];
    const int* tref_ptr = (const int*)d_in[3];
    float* out = (float*)d_out;

    const size_t BN = (size_t)BB * NN;   // 2.4576 M cells
    // ws layout: Sw|Swy|Swx | fxy2 (BN*8B) | llist (NBLOCKS*SEGCAP*16B) | segcnt
    const size_t s_bytes = 3 * BN * sizeof(float);                  // 29.49 MB
    const size_t f_bytes = BN * sizeof(float2);                     // 19.66 MB
    const size_t l_bytes = (size_t)NBLOCKS * SEGCAP * sizeof(int4); // 19.66 MB
    const size_t need = s_bytes + f_bytes + l_bytes + NBLOCKS * sizeof(unsigned);
    if (ws_size >= need) {
        float* Sw  = (float*)d_ws;
        float* Swy = Sw  + BN;
        float* Swx = Swy + BN;
        float2* fxy2 = (float2*)((char*)d_ws + s_bytes);
        int4* llist = (int4*)((char*)fxy2 + f_bytes);
        unsigned* segcnt = (unsigned*)((char*)llist + l_bytes);

        // no memsets: segcnt/fxy2/S/out all written unconditionally.
        int itotal = (int)(BN / 4);
        interleave_flow<<<(itotal + 255) / 256, 256, 0, stream>>>(
            fx_all, fy_all, i_ptr, fxy2);
        dim3 grid(NBX, NBY, BB);
        bin_gather_splat<<<grid, NT, 0, stream>>>(fxy2, i_ptr, tref_ptr,
                                                  Sw, Swy, Swx, segcnt, llist, out);
        // small grid-stride fix kernels (~30K real entries; the 1.23M-slot
        // scan doesn't need 307K threads)
        fix_add<<<128, 256, 0, stream>>>(segcnt, llist, Sw, Swy, Swx);
        fix_write<<<128, 256, 0, stream>>>(segcnt, llist, Sw, Swy, Swx, out);
    } else {
        // R1 fallback: global-atomic splat (native adds)
        float* sum_w  = (float*)d_ws;
        float* sum_wy = sum_w + BN;
        float* sum_wx = sum_wy + BN;
        hipMemsetAsync(d_ws, 0, 3 * BN * sizeof(float), stream);
        int total = (int)BN;
        int block = 256;
        int grid1 = (total + block - 1) / block;
        splat_kernel<<<grid1, block, 0, stream>>>(fx_all, fy_all, i_ptr, tref_ptr,
                                                  sum_w, sum_wy, sum_wx);
        finalize_kernel<<<grid1, block, 0, stream>>>(sum_w, sum_wy, sum_wx, out);
    }
}

// Round 21
// 64.452 us; speedup vs baseline: 1.7235x; 1.7235x over previous
//
#include <hip/hip_runtime.h>
#include <stdint.h>

// Problem constants (fixed by the reference's config)
#define HH 480
#define WW 640
#define NN (HH * WW)
#define BB 8
#define PP 4
#define EPS 1e-9f

// Output-tile geometry: block owns a TW x TH OUTPUT tile. 640/64=10, 480/32=15.
#define TW 64
#define TH 32
#define HALO 12
#define RGW (TW + 2 * HALO)   // 88
#define RGH (TH + 2 * HALO)   // 56
#define RGN (RGW * RGH)       // 4928
#define NBX (WW / TW)         // 10
#define NBY (HH / TH)         // 15
#define NBLOCKS (NBX * NBY * BB)  // 1200
#define NT 512                // threads/block (8 waves) -- R17-proven config

// Binning: sources bucketed by floor cell.
#define BINSX (TW + 1)        // 65
#define BINSY (TH + 1)        // 33
#define NBINS (BINSX * BINSY) // 2145
#define CAP 4                 // slots/bin; P(>4)~0.4% -> list path

// guaranteed-in-image source id (rel HALO,HALO) for dead predicated loads
#define SAFE_ID ((HALO << 7) | HALO)

// per-block far/overflow segment. Measured usage: mean ~97 entries (24 far
// sources x 4 nbrs), sigma ~20. 512 = mean + 20 sigma. (1024 was 45 sigma --
// halving the fix-kernel scan volume. R20's 128-block fix grid was the real
// regression: 37 serial slots/thread at 2 waves/CU, latency-bound.)
#define SEGCAP 512

__device__ __forceinline__ void gatomic(float* p, float v) {
    unsafeAtomicAdd(p, v);    // native global_atomic_add_f32, rare path only
}

// ---------------- pre-pass: interleave the i-th flow plane ----------------
__global__ __launch_bounds__(256)
void interleave_flow(const float* __restrict__ fx_all,
                     const float* __restrict__ fy_all,
                     const int* __restrict__ i_ptr,
                     float2* __restrict__ fxy2) {
    int t = blockIdx.x * blockDim.x + threadIdx.x;   // one thread per 4 pixels
    const int Q = NN / 4;
    if (t >= BB * Q) return;
    int b = t / Q, q = t - b * Q;
    int i = *i_ptr;
    const float4* fyp = (const float4*)(fy_all + (size_t)(b * PP + i) * NN);
    const float4* fxp = (const float4*)(fx_all + (size_t)(b * PP + i) * NN);
    float4 y4 = fyp[q], x4 = fxp[q];
    float4* o4 = (float4*)(fxy2 + (size_t)b * NN + (size_t)q * 4);
    o4[0] = make_float4(y4.x, x4.x, y4.y, x4.y);
    o4[1] = make_float4(y4.z, x4.z, y4.w, x4.w);
}

// Phase A: scan halo region, bin sources by floor cell (1 LDS rtn-atomic per
// source); far/overflow appended to this block's list segment (conservative
// |warp-src|>11 pre-guard). Phase B: 4-row column strip per thread,
// register-cached bin rows (named float4 ping-pong). All warp/weight
// expressions bit-identical to phase A / the reference.
__global__ __launch_bounds__(NT, 8)
void bin_gather_splat(const float2* __restrict__ fxy2,
                      const int* __restrict__ i_ptr,
                      const int* __restrict__ tref_ptr,
                      float* __restrict__ Sw, float* __restrict__ Swy, float* __restrict__ Swx,
                      unsigned* __restrict__ segcnt, int4* __restrict__ llist,
                      float* __restrict__ out) {
    __shared__ unsigned cnt[NBINS];   // 8580 B
    __shared__ ushort4  ids4[NBINS];  // 17160 B
    __shared__ unsigned lseg;
    const int tid = threadIdx.x;
    for (int e = tid; e < NBINS; e += NT) cnt[e] = 0;
    if (tid == 0) lseg = 0;
    __syncthreads();

    const int bx = blockIdx.x, by = blockIdx.y, b = blockIdx.z;
    const int bid = (b * NBY + by) * NBX + bx;
    int4* __restrict__ lseg_base = llist + (size_t)bid * SEGCAP;
    const int tx0 = bx * TW, ty0 = by * TH;
    const float dt = (float)(*tref_ptr - *i_ptr);
    const float2* __restrict__ fp2 = fxy2 + (size_t)b * NN;
    const size_t BN = (size_t)BB * NN;

    // ---------------- phase A ----------------
    for (int sp = tid; sp < RGN; sp += NT) {
        int sy = sp / RGW, sx = sp - sy * RGW;
        int gy = ty0 - HALO + sy, gx = tx0 - HALO + sx;
        if ((unsigned)gy >= (unsigned)HH || (unsigned)gx >= (unsigned)WW) continue;
        int p = gy * WW + gx;
        float2 f2 = fp2[p];
        float fy = f2.x, fx = f2.y;
        float wyf = (float)gy + dt * fy;
        float wxf = (float)gx + dt * fx;
        // purge_unfeasible
        if (!(wyf >= 0.0f && wyf <= (float)(HH - 1) &&
              wxf >= 0.0f && wxf <= (float)(WW - 1))) continue;
        float tyf = floorf(wyf), lxf = floorf(wxf);
        int iy0 = (int)tyf, ix0 = (int)lxf;   // >= 0 (inside test)
        int br = iy0 - ty0, bc = ix0 - tx0;

        bool overflow = false;
        if (br >= -1 && br < TH && bc >= -1 && bc < TW) {
            int bin = (br + 1) * BINSX + (bc + 1);
            unsigned slot = atomicAdd(&cnt[bin], 1u);   // native ds_add_rtn_u32
            if (slot < CAP)
                ((unsigned short*)&ids4[bin])[slot] = (unsigned short)((sy << 7) | sx);
            else overflow = true;
        }
        bool interior = ((unsigned)(gx - tx0) < (unsigned)TW) &&
                        ((unsigned)(gy - ty0) < (unsigned)TH);
        // conservative far pre-guard: any far (s,N) pair has |warp-s|inf >= 12
        bool maybe_far = (fabsf(wyf - (float)gy) > 11.0f) ||
                         (fabsf(wxf - (float)gx) > 11.0f);
        if (overflow || (interior && maybe_far)) {
            float fry = wyf - tyf, frx = wxf - lxf;
            float wts[4] = {(1.0f - fry) * (1.0f - frx),
                            (1.0f - fry) * frx,
                            fry * (1.0f - frx),
                            fry * frx};
#pragma unroll
            for (int k = 0; k < 4; ++k) {
                int iy = iy0 + (k >> 1), ix = ix0 + (k & 1);
                if ((unsigned)iy >= (unsigned)HH || (unsigned)ix >= (unsigned)WW) continue;
                bool inT = ((unsigned)(iy - ty0) < (unsigned)TH) &&
                           ((unsigned)(ix - tx0) < (unsigned)TW);
                // far: s's owner must emit (tile(N) never scans s)
                int tnx = (ix >> 6) << 6;   // tile(N) origin, TW=64
                int tny = (iy >> 5) << 5;   // TH=32
                int ddx = gx < tnx ? tnx - gx : (gx > tnx + (TW - 1) ? gx - tnx - (TW - 1) : 0);
                int ddy = gy < tny ? tny - gy : (gy > tny + (TH - 1) ? gy - tny - (TH - 1) : 0);
                bool far = (ddx > HALO) || (ddy > HALO);
                if ((interior && far) || (overflow && inT)) {
                    int fi = b * NN + iy * WW + ix;
                    float w = wts[k];
                    unsigned slot = atomicAdd(&lseg, 1u);   // LDS rtn-atomic
                    if (slot < SEGCAP)
                        lseg_base[slot] = make_int4(fi, __float_as_int(w),
                                                    __float_as_int(w * fy),
                                                    __float_as_int(w * fx));
                }
            }
        }
    }
    __syncthreads();
    if (tid == 0) segcnt[bid] = lseg > SEGCAP ? SEGCAP : lseg;

    // ---------------- phase B: 4-row strip, register-cached gather ----------------
    {
        const int c  = tid & 63;          // column within tile (wave-coalesced)
        const int r0 = (tid >> 6) * 4;    // tid>>6 in 0..7 -> 4-row strips cover 32
        const float cxf = (float)(tx0 + c);

#define LOAD_SLOT(dst, idraw, nn, T) {                                        \
        bool valid = (unsigned)(T) < (nn);                                    \
        int sid = valid ? (int)(idraw) : SAFE_ID;                             \
        int sy_ = sid >> 7, sx_ = sid & 127;                                  \
        int gy_ = ty0 - HALO + sy_, gx_ = tx0 - HALO + sx_;                   \
        float2 f2_ = fp2[gy_ * WW + gx_];                                     \
        float wyf_ = (float)gy_ + dt * f2_.x;                                 \
        float wxf_ = (float)gx_ + dt * f2_.y;                                 \
        dst.x = valid ? wyf_ : -1.0e6f;  /* ay=0 -> w=0 */                    \
        dst.y = wxf_;                                                         \
        dst.z = f2_.x; dst.w = f2_.y; }

#define LOAD_ROW(d0,d1,d2,d3,d4,d5,d6,d7, brow) {                             \
        int bin0_ = (brow) * BINSX + c;                                       \
        unsigned na_ = cnt[bin0_];     ushort4 sa_ = ids4[bin0_];             \
        unsigned nb_ = cnt[bin0_ + 1]; ushort4 sb_ = ids4[bin0_ + 1];         \
        LOAD_SLOT(d0, sa_.x, na_, 0); LOAD_SLOT(d1, sa_.y, na_, 1);           \
        LOAD_SLOT(d2, sa_.z, na_, 2); LOAD_SLOT(d3, sa_.w, na_, 3);           \
        LOAD_SLOT(d4, sb_.x, nb_, 0); LOAD_SLOT(d5, sb_.y, nb_, 1);           \
        LOAD_SLOT(d6, sb_.z, nb_, 2); LOAD_SLOT(d7, sb_.w, nb_, 3); }

// indirection wrappers: register lists literal in replacement text
// (macro arg counting precedes expansion -- R15 lesson)
#define LOAD_ROW_A(brow) LOAD_ROW(a0,a1,a2,a3,a4,a5,a6,a7, brow)
#define LOAD_ROW_B(brow) LOAD_ROW(b0,b1,b2,b3,b4,b5,b6,b7, brow)

#define EVAL_SLOT(S) {                                                        \
        float ay_ = fmaxf(1.0f - fabsf(S.x - cyf), 0.0f);                     \
        float ax_ = fmaxf(1.0f - fabsf(S.y - cxf), 0.0f);                     \
        float w_ = ay_ * ax_;                                                 \
        ws += w_; wys += w_ * S.z; wxs += w_ * S.w; }

        // X set = bin row r, Y set = bin row r+1
#define EVAL_CELL(X0,X1,X2,X3,X4,X5,X6,X7, Y0,Y1,Y2,Y3,Y4,Y5,Y6,Y7, rowr) {   \
        float cyf = (float)(ty0 + (rowr));                                    \
        float ws = 0.f, wys = 0.f, wxs = 0.f;                                 \
        EVAL_SLOT(X0); EVAL_SLOT(X1); EVAL_SLOT(X2); EVAL_SLOT(X3);           \
        EVAL_SLOT(X4); EVAL_SLOT(X5); EVAL_SLOT(X6); EVAL_SLOT(X7);           \
        EVAL_SLOT(Y0); EVAL_SLOT(Y1); EVAL_SLOT(Y2); EVAL_SLOT(Y3);           \
        EVAL_SLOT(Y4); EVAL_SLOT(Y5); EVAL_SLOT(Y6); EVAL_SLOT(Y7);           \
        size_t o = (size_t)b * NN + (size_t)(ty0 + (rowr)) * WW + (tx0 + c);  \
        Sw[o] = ws; Swy[o] = wys; Swx[o] = wxs;                               \
        float d = ws + EPS;                                                   \
        out[o]      = wxs / d;                                                \
        out[BN + o] = wys / d; }

#define EVAL_CELL_AB(rowr) EVAL_CELL(a0,a1,a2,a3,a4,a5,a6,a7, \
                                     b0,b1,b2,b3,b4,b5,b6,b7, rowr)
#define EVAL_CELL_BA(rowr) EVAL_CELL(b0,b1,b2,b3,b4,b5,b6,b7, \
                                     a0,a1,a2,a3,a4,a5,a6,a7, rowr)

        float4 a0,a1,a2,a3,a4,a5,a6,a7;
        float4 b0,b1,b2,b3,b4,b5,b6,b7;
        LOAD_ROW_A(r0);
        LOAD_ROW_B(r0 + 1);
        EVAL_CELL_AB(r0 + 0);  LOAD_ROW_A(r0 + 2);
        EVAL_CELL_BA(r0 + 1);  LOAD_ROW_B(r0 + 3);
        EVAL_CELL_AB(r0 + 2);  LOAD_ROW_A(r0 + 4);
        EVAL_CELL_BA(r0 + 3);
#undef LOAD_SLOT
#undef LOAD_ROW
#undef LOAD_ROW_A
#undef LOAD_ROW_B
#undef EVAL_SLOT
#undef EVAL_CELL
#undef EVAL_CELL_AB
#undef EVAL_CELL_BA
    }
}

// ---------------- fixups for list-touched pixels (grid-stride) ----------------
__global__ __launch_bounds__(256)
void fix_add(const unsigned* __restrict__ segcnt, const int4* __restrict__ llist,
             float* __restrict__ Sw, float* __restrict__ Swy, float* __restrict__ Swx) {
    const unsigned total = NBLOCKS * SEGCAP;
    const unsigned stride = gridDim.x * blockDim.x;
    for (unsigned e = blockIdx.x * blockDim.x + threadIdx.x; e < total; e += stride) {
        unsigned seg = e / SEGCAP, idx = e & (SEGCAP - 1);
        if (idx >= segcnt[seg]) continue;
        int4 v = llist[e];
        gatomic(&Sw[v.x],  __int_as_float(v.y));
        gatomic(&Swy[v.x], __int_as_float(v.z));
        gatomic(&Swx[v.x], __int_as_float(v.w));
    }
}

__global__ __launch_bounds__(256)
void fix_write(const unsigned* __restrict__ segcnt, const int4* __restrict__ llist,
               const float* __restrict__ Sw, const float* __restrict__ Swy,
               const float* __restrict__ Swx, float* __restrict__ out) {
    const unsigned total = NBLOCKS * SEGCAP;
    const unsigned stride = gridDim.x * blockDim.x;
    for (unsigned e = blockIdx.x * blockDim.x + threadIdx.x; e < total; e += stride) {
        unsigned seg = e / SEGCAP, idx = e & (SEGCAP - 1);
        if (idx >= segcnt[seg]) continue;
        int fi = llist[e].x;                  // duplicates benign (idempotent)
        float d = Sw[fi] + EPS;
        out[fi] = Swx[fi] / d;
        out[(size_t)BB * NN + fi] = Swy[fi] / d;
    }
}

// ---------------- fallback path (R1, needs only 29.5 MB ws) ----------------

__global__ void splat_kernel(const float* __restrict__ fx_all,
                             const float* __restrict__ fy_all,
                             const int* __restrict__ i_ptr,
                             const int* __restrict__ tref_ptr,
                             float* __restrict__ sum_w,
                             float* __restrict__ sum_wy,
                             float* __restrict__ sum_wx) {
    int t = blockIdx.x * blockDim.x + threadIdx.x;
    if (t >= BB * NN) return;
    int b = t / NN;
    int p = t - b * NN;
    int i = *i_ptr;
    float dt = (float)(*tref_ptr - i);
    const float fx = fx_all[(size_t)(b * PP + i) * NN + p];
    const float fy = fy_all[(size_t)(b * PP + i) * NN + p];
    float gy = (float)(p / WW);
    float gx = (float)(p - (p / WW) * WW);
    float wy = gy + dt * fy;
    float wx = gx + dt * fx;
    bool inside = (wy >= 0.0f) && (wy <= (float)(HH - 1)) &&
                  (wx >= 0.0f) && (wx <= (float)(WW - 1));
    if (!inside) return;
    float ty = floorf(wy);
    float lx = floorf(wx);
    int base = b * NN;
#pragma unroll
    for (int k = 0; k < 4; ++k) {
        float ny = ty + (float)(k >> 1);
        float nx = lx + (float)(k & 1);
        int iy = (int)ny;
        int ix = (int)nx;
        if (iy < 0 || iy >= HH || ix < 0 || ix >= WW) continue;
        float wgt_y = fminf(fmaxf(1.0f - fabsf(wy - ny), 0.0f), 1.0f);
        float wgt_x = fminf(fmaxf(1.0f - fabsf(wx - nx), 0.0f), 1.0f);
        float w = wgt_y * wgt_x;
        int fi = base + iy * WW + ix;
        gatomic(&sum_w[fi],  w);
        gatomic(&sum_wy[fi], w * fy);
        gatomic(&sum_wx[fi], w * fx);
    }
}

__global__ void finalize_kernel(const float* __restrict__ sum_w,
                                const float* __restrict__ sum_wy,
                                const float* __restrict__ sum_wx,
                                float* __restrict__ out) {
    int t = blockIdx.x * blockDim.x + threadIdx.x;
    if (t >= BB * NN) return;
    float denom = sum_w[t] + EPS;
    out[t]                   = sum_wx[t] / denom;
    out[(size_t)BB * NN + t] = sum_wy[t] / denom;
}

// ---------------- launch ----------------

extern "C" void kernel_launch(void* const* d_in, const int* in_sizes, int n_in,
                              void* d_out, int out_size, void* d_ws, size_t ws_size,
                              hipStream_t stream) {
    const float* fx_all = (const float*)d_in[0];
    const float* fy_all = (const float*)d_in[1];
    const int* i_ptr    = (const int*)d_in[2];
    const int* tref_ptr = (const int*)d_in[3];
    float* out = (float*)d_out;

    const size_t BN = (size_t)BB * NN;   // 2.4576 M cells
    // ws layout: Sw|Swy|Swx | fxy2 (BN*8B) | llist (NBLOCKS*SEGCAP*16B) | segcnt
    const size_t s_bytes = 3 * BN * sizeof(float);                  // 29.49 MB
    const size_t f_bytes = BN * sizeof(float2);                     // 19.66 MB
    const size_t l_bytes = (size_t)NBLOCKS * SEGCAP * sizeof(int4); // 9.83 MB
    const size_t need = s_bytes + f_bytes + l_bytes + NBLOCKS * sizeof(unsigned);
    if (ws_size >= need) {
        float* Sw  = (float*)d_ws;
        float* Swy = Sw  + BN;
        float* Swx = Swy + BN;
        float2* fxy2 = (float2*)((char*)d_ws + s_bytes);
        int4* llist = (int4*)((char*)fxy2 + f_bytes);
        unsigned* segcnt = (unsigned*)((char*)llist + l_bytes);

        // no memsets: segcnt/fxy2/S/out all written unconditionally.
        int itotal = (int)(BN / 4);
        interleave_flow<<<(itotal + 255) / 256, 256, 0, stream>>>(
            fx_all, fy_all, i_ptr, fxy2);
        dim3 grid(NBX, NBY, BB);
        bin_gather_splat<<<grid, NT, 0, stream>>>(fxy2, i_ptr, tref_ptr,
                                                  Sw, Swy, Swx, segcnt, llist, out);
        // grid-stride fix kernels at R18-proven geometry: 1200 blocks x 256,
        // now 2 slots/thread over the halved 614.4K-slot list space
        fix_add<<<NBLOCKS, 256, 0, stream>>>(segcnt, llist, Sw, Swy, Swx);
        fix_write<<<NBLOCKS, 256, 0, stream>>>(segcnt, llist, Sw, Swy, Swx, out);
    } else {
        // R1 fallback: global-atomic splat (native adds)
        float* sum_w  = (float*)d_ws;
        float* sum_wy = sum_w + BN;
        float* sum_wx = sum_wy + BN;
        hipMemsetAsync(d_ws, 0, 3 * BN * sizeof(float), stream);
        int total = (int)BN;
        int block = 256;
        int grid1 = (total + block - 1) / block;
        splat_kernel<<<grid1, block, 0, stream>>>(fx_all, fy_all, i_ptr, tref_ptr,
                                                  sum_w, sum_wy, sum_wx);
        finalize_kernel<<<grid1, block, 0, stream>>>(sum_w, sum_wy, sum_wx, out);
    }
}